// Round 10
// baseline (965.750 us; speedup 1.0000x reference)
//
#include <hip/hip_runtime.h>

#define LRELU(x) ((x) > 0.f ? (x) : 0.01f * (x))

constexpr int C = 32;
constexpr int BSH = 8;            // 256 dst-nodes per bucket
constexpr int MAXBK = 512;        // max buckets (N <= 131072)

typedef int   iv4 __attribute__((ext_vector_type(4)));
typedef float fv2 __attribute__((ext_vector_type(2)));

// ---- bf16 pack/unpack helpers ----
__device__ __forceinline__ unsigned pk_bf16(float a, float b) {
    unsigned ua = __float_as_uint(a), ub = __float_as_uint(b);
    unsigned ra = (ua + 0x7fffu + ((ua >> 16) & 1u)) >> 16;
    unsigned rb = (ub + 0x7fffu + ((ub >> 16) & 1u)) & 0xffff0000u;
    return ra | rb;
}
__device__ __forceinline__ float lo_bf16(unsigned w) { return __uint_as_float(w << 16); }
__device__ __forceinline__ float hi_bf16(unsigned w) { return __uint_as_float(w & 0xffff0000u); }

// ---- bucket histogram (LDS-privatized) ----
__global__ void k_bhist(const int* __restrict__ col, int* __restrict__ ghist, int E) {
    __shared__ int lh[MAXBK];
    for (int i = threadIdx.x; i < MAXBK; i += blockDim.x) lh[i] = 0;
    __syncthreads();
    int chunk = (E + gridDim.x - 1) / gridDim.x;
    int c0 = blockIdx.x * chunk, c1 = min(E, c0 + chunk);
    for (int e = c0 + threadIdx.x; e < c1; e += blockDim.x)
        atomicAdd(&lh[col[e] >> BSH], 1);
    __syncthreads();
    for (int i = threadIdx.x; i < MAXBK; i += blockDim.x) {
        int v = lh[i];
        if (v) atomicAdd(&ghist[i], v);
    }
}

// ---- exclusive scan of bucket counts -> bbase, gcur ----
__global__ void k_bscan(const int* __restrict__ ghist, int* __restrict__ bbase,
                        int* __restrict__ gcur, int nbk, int E) {
    __shared__ int sm[MAXBK];
    int tid = threadIdx.x;
    int v = (tid < nbk) ? ghist[tid] : 0;
    sm[tid] = v;
    __syncthreads();
    for (int off = 1; off < MAXBK; off <<= 1) {
        int t = (tid >= off) ? sm[tid - off] : 0;
        __syncthreads();
        sm[tid] += t;
        __syncthreads();
    }
    if (tid < nbk) {
        int excl = sm[tid] - v;
        bbase[tid] = excl;
        gcur[tid] = excl;
    }
    if (tid == 0) bbase[nbk] = E;
}

// ---- partition edges into buckets; per-wg claimed contiguous runs ----
// tmp entry: { src | (dstLow8 << 17), ea_bits }
__global__ void k_part(const int* __restrict__ row, const int* __restrict__ col,
                       const float* __restrict__ ea, int* __restrict__ gcur,
                       int2* __restrict__ tmp, int E) {
    __shared__ int lcnt[MAXBK];
    __shared__ int lbase[MAXBK];
    __shared__ int lcur[MAXBK];
    for (int i = threadIdx.x; i < MAXBK; i += blockDim.x) { lcnt[i] = 0; lcur[i] = 0; }
    __syncthreads();
    int chunk = (E + gridDim.x - 1) / gridDim.x;
    int c0 = blockIdx.x * chunk, c1 = min(E, c0 + chunk);
    for (int e = c0 + threadIdx.x; e < c1; e += blockDim.x)
        atomicAdd(&lcnt[col[e] >> BSH], 1);
    __syncthreads();
    for (int b = threadIdx.x; b < MAXBK; b += blockDim.x) {
        int c = lcnt[b];
        lbase[b] = c ? atomicAdd(&gcur[b], c) : 0;
    }
    __syncthreads();
    for (int e = c0 + threadIdx.x; e < c1; e += blockDim.x) {
        int cc = col[e];
        int b = cc >> BSH;
        int r = atomicAdd(&lcur[b], 1);
        tmp[lbase[b] + r] = make_int2(row[e] | ((cc & 255) << 17), __float_as_int(ea[e]));
    }
}

// ---- per-bucket CSR build ----
__global__ void k_build(const int* __restrict__ bbase, const int2* __restrict__ tmp,
                        int* __restrict__ rowptr, float* __restrict__ dinv,
                        int2* __restrict__ pairs, int N, int E) {
    __shared__ int ncnt[256], noff[256], ncur[256], scn[256];
    __shared__ float ndeg[256];
    int tid = threadIdx.x;
    int bg = blockIdx.x;
    int node0 = bg << BSH;
    int s = bbase[bg], e = bbase[bg + 1];
    ncnt[tid] = 0; ncur[tid] = 0; ndeg[tid] = 0.f;
    __syncthreads();
    for (int p = s + tid; p < e; p += 256) {
        int2 u = tmp[p];
        int nl = (u.x >> 17) & 255;
        atomicAdd(&ncnt[nl], 1);
        atomicAdd(&ndeg[nl], __int_as_float(u.y));
    }
    __syncthreads();
    int v = ncnt[tid];
    scn[tid] = v;
    __syncthreads();
    for (int off = 1; off < 256; off <<= 1) {
        int t = (tid >= off) ? scn[tid - off] : 0;
        __syncthreads();
        scn[tid] += t;
        __syncthreads();
    }
    {
        int excl = scn[tid] - v;
        noff[tid] = excl;
        int node = node0 + tid;
        if (node < N) {
            rowptr[node] = s + excl;
            float d = ndeg[tid];
            dinv[node] = d > 0.f ? rsqrtf(fmaxf(d, 1e-12f)) : 0.f;
        }
    }
    if (bg == gridDim.x - 1 && tid == 0) rowptr[N] = E;
    __syncthreads();
    for (int p = s + tid; p < e; p += 256) {
        int2 u = tmp[p];
        int nl = (u.x >> 17) & 255;
        int r = atomicAdd(&ncur[nl], 1);
        pairs[s + noff[nl] + r] = make_int2(u.x & 0x1FFFF, u.y);
    }
}

// ---- read-in MLP: h = lrelu([state,action]@W_in+b_in); v split into lo/hi halves ----
__global__ void k_inmlp(const float* __restrict__ state, const float* __restrict__ action,
                        const float* __restrict__ Win, const float* __restrict__ bin,
                        const float* __restrict__ dinv,
                        float* __restrict__ h, unsigned* __restrict__ vlo,
                        unsigned* __restrict__ vhi, int N) {
    int t = blockIdx.x * blockDim.x + threadIdx.x;
    int i = t >> 5, c = t & 31;
    if (i >= N) return;
    float acc = bin[c];
#pragma unroll
    for (int d = 0; d < 8; ++d) acc += state[i * 8 + d] * Win[d * 32 + c];
#pragma unroll
    for (int d = 0; d < 2; ++d) acc += action[i * 2 + d] * Win[(8 + d) * 32 + c];
    float hv = LRELU(acc);
    h[i * 32 + c] = hv;
    float vv = dinv[i] * hv;
    float other = __shfl_xor(vv, 1, 32);
    if ((c & 1) == 0) {
        unsigned u = pk_bf16(vv, other);
        int j = c >> 1;                         // pair index 0..15
        if (j < 8) vlo[((size_t)i << 3) + j] = u;
        else       vhi[((size_t)i << 3) + (j - 8)] = u;
    }
}

// ---- pipelined half-table gather: lane q owns half-channels {2q,2q+1} ----
__device__ __forceinline__ fv2 gather_half(int s, int e, const int2* __restrict__ pairs,
                                           const unsigned* __restrict__ vhalf, int q) {
    fv2 tv = {0.f, 0.f};
    int p = s;
    if ((p & 1) && p < e) {                 // peel to 16B-aligned pair index
        int2 pr = pairs[p];
        unsigned x = vhalf[((size_t)(unsigned)pr.x << 3) + q];
        float w = __int_as_float(pr.y);
        tv.x += w * lo_bf16(x); tv.y += w * hi_bf16(x);
        ++p;
    }
#pragma unroll 2
    for (; p + 4 <= e; p += 4) {            // 4 edges: 2 nt pair-loads, 4 uint gathers
        iv4 pa = __builtin_nontemporal_load((const iv4*)&pairs[p]);
        iv4 pb = __builtin_nontemporal_load((const iv4*)&pairs[p + 2]);
        unsigned x0 = vhalf[((size_t)(unsigned)pa[0] << 3) + q];
        unsigned x1 = vhalf[((size_t)(unsigned)pa[2] << 3) + q];
        unsigned x2 = vhalf[((size_t)(unsigned)pb[0] << 3) + q];
        unsigned x3 = vhalf[((size_t)(unsigned)pb[2] << 3) + q];
        float w0 = __int_as_float(pa[1]), w1 = __int_as_float(pa[3]);
        float w2 = __int_as_float(pb[1]), w3 = __int_as_float(pb[3]);
        tv.x += w0 * lo_bf16(x0) + w1 * lo_bf16(x1) + w2 * lo_bf16(x2) + w3 * lo_bf16(x3);
        tv.y += w0 * hi_bf16(x0) + w1 * hi_bf16(x1) + w2 * hi_bf16(x2) + w3 * hi_bf16(x3);
    }
    for (; p < e; ++p) {                    // tail singles
        int2 pr = pairs[p];
        unsigned x = vhalf[((size_t)(unsigned)pr.x << 3) + q];
        float w = __int_as_float(pr.y);
        tv.x += w * lo_bf16(x); tv.y += w * hi_bf16(x);
    }
    return tv;
}

// ---- tap phase A: gather lo half-table only; write z-lo scratch (+ next lo table) ----
__global__ void k_tapA(const int* __restrict__ rowptr, const int2* __restrict__ pairs,
                       const unsigned* __restrict__ vlo, const float* __restrict__ dinv,
                       fv2* __restrict__ zA, unsigned* __restrict__ vloNext,
                       int N, int last) {
    int t = blockIdx.x * blockDim.x + threadIdx.x;
    int g = t >> 3, q = t & 7;
    if (g >= N) return;
    fv2 tv = gather_half(rowptr[g], rowptr[g + 1], pairs, vlo, q);
    float di = dinv[g];
    fv2 z = {di * tv.x, di * tv.y};
    __builtin_nontemporal_store(z, &zA[((size_t)g << 3) + q]);
    if (!last) vloNext[((size_t)g << 3) + q] = pk_bf16(di * z.x, di * z.y);
}

// acc(4 cols) += h(row, spread over 8 lanes as float4) @ W(32x32), cols 4q..4q+3
__device__ __forceinline__ void mm_acc(float4& acc, float4 zq,
                                       const float* __restrict__ W, int q) {
#pragma unroll
    for (int a = 0; a < 8; ++a) {
        float z0 = __shfl(zq.x, a, 8), z1 = __shfl(zq.y, a, 8);
        float z2 = __shfl(zq.z, a, 8), z3 = __shfl(zq.w, a, 8);
        const float4 w0 = *(const float4*)&W[(4 * a + 0) * 32 + 4 * q];
        const float4 w1 = *(const float4*)&W[(4 * a + 1) * 32 + 4 * q];
        const float4 w2 = *(const float4*)&W[(4 * a + 2) * 32 + 4 * q];
        const float4 w3 = *(const float4*)&W[(4 * a + 3) * 32 + 4 * q];
        acc.x += z0 * w0.x + z1 * w1.x + z2 * w2.x + z3 * w3.x;
        acc.y += z0 * w0.y + z1 * w1.y + z2 * w2.y + z3 * w3.y;
        acc.z += z0 * w0.z + z1 * w1.z + z2 * w2.z + z3 * w3.z;
        acc.w += z0 * w0.w + z1 * w1.w + z2 * w2.w + z3 * w3.w;
    }
}

// ---- tap phase B: gather hi half-table; combine with z-lo; matmul + epilogue ----
__global__ void k_tapB(const int* __restrict__ rowptr, const int2* __restrict__ pairs,
                       const unsigned* __restrict__ vhi, const float* __restrict__ hin,
                       const float* __restrict__ dinv, const fv2* __restrict__ zA,
                       float* __restrict__ outacc, unsigned* __restrict__ vhiNext,
                       unsigned* __restrict__ vloL, unsigned* __restrict__ vhiL,
                       float* __restrict__ hout, float* __restrict__ yout,
                       const float* __restrict__ Wl, int k, const float* __restrict__ bias,
                       const float* __restrict__ Wout, const float* __restrict__ bout,
                       int N, int first, int last, int readout) {
    int t = blockIdx.x * blockDim.x + threadIdx.x;
    int g = t >> 3, q = t & 7;
    if (g >= N) return;
    fv2 tv = gather_half(rowptr[g], rowptr[g + 1], pairs, vhi, q);
    float di = dinv[g];
    float zh0 = di * tv.x, zh1 = di * tv.y;
    fv2 zl = __builtin_nontemporal_load(&zA[((size_t)g << 3) + q]);
    const float* Wk = Wl + (size_t)k * 1024;
    float4 acc;
    if (first) {
        acc = *(const float4*)&bias[4 * q];
        float4 hq = *(const float4*)&hin[(size_t)g * 32 + 4 * q];
        mm_acc(acc, hq, Wl, q);
    } else {
        acc = *(const float4*)&outacc[(size_t)g * 32 + 4 * q];
    }
    // combined z (lo from zA, hi just gathered) @ Wk
#pragma unroll
    for (int a = 0; a < 8; ++a) {
        float l0 = __shfl(zl.x, a, 8), l1 = __shfl(zl.y, a, 8);
        float h0 = __shfl(zh0, a, 8), h1 = __shfl(zh1, a, 8);
        const float4 w0 = *(const float4*)&Wk[(2 * a + 0) * 32 + 4 * q];
        const float4 w1 = *(const float4*)&Wk[(2 * a + 1) * 32 + 4 * q];
        const float4 w2 = *(const float4*)&Wk[(16 + 2 * a) * 32 + 4 * q];
        const float4 w3 = *(const float4*)&Wk[(17 + 2 * a) * 32 + 4 * q];
        acc.x += l0 * w0.x + l1 * w1.x + h0 * w2.x + h1 * w3.x;
        acc.y += l0 * w0.y + l1 * w1.y + h0 * w2.y + h1 * w3.y;
        acc.z += l0 * w0.z + l1 * w1.z + h0 * w2.z + h1 * w3.z;
        acc.w += l0 * w0.w + l1 * w1.w + h0 * w2.w + h1 * w3.w;
    }
    if (!last) {
        *(float4*)&outacc[(size_t)g * 32 + 4 * q] = acc;
        vhiNext[((size_t)g << 3) + q] = pk_bf16(di * zh0, di * zh1);
    } else {
        float4 hv = {LRELU(acc.x), LRELU(acc.y), LRELU(acc.z), LRELU(acc.w)};
        if (!readout) {
            *(float4*)&hout[(size_t)g * 32 + 4 * q] = hv;
            unsigned u0 = pk_bf16(di * hv.x, di * hv.y);
            unsigned u1 = pk_bf16(di * hv.z, di * hv.w);
            if (q < 4) {
                vloL[((size_t)g << 3) + 2 * q] = u0;
                vloL[((size_t)g << 3) + 2 * q + 1] = u1;
            } else {
                vhiL[((size_t)g << 3) + 2 * (q - 4)] = u0;
                vhiL[((size_t)g << 3) + 2 * (q - 4) + 1] = u1;
            }
        } else {
            const float4 w4 = *(const float4*)&Wout[4 * q];
            float v = hv.x * w4.x + hv.y * w4.y + hv.z * w4.z + hv.w * w4.w;
            v += __shfl_xor(v, 4, 8);
            v += __shfl_xor(v, 2, 8);
            v += __shfl_xor(v, 1, 8);
            if (q == 0) yout[g] = v + bout[0];
        }
    }
}

// ---- segmented mean over sorted batch: one block per graph ----
__global__ void k_segmean(const float* __restrict__ y, const int* __restrict__ batch,
                          float* __restrict__ out, int N) {
    int b = blockIdx.x;
    __shared__ int slo, shi;
    if (threadIdx.x == 0) {
        int lo = 0, hi = N;
        while (lo < hi) { int m = (lo + hi) >> 1; if (batch[m] < b) lo = m + 1; else hi = m; }
        slo = lo;
        hi = N;
        while (lo < hi) { int m = (lo + hi) >> 1; if (batch[m] < b + 1) lo = m + 1; else hi = m; }
        shi = lo;
    }
    __syncthreads();
    int lo = slo, hi = shi;
    float sum = 0.f;
    for (int i = lo + threadIdx.x; i < hi; i += blockDim.x) sum += y[i];
    __shared__ float sm[256];
    sm[threadIdx.x] = sum;
    __syncthreads();
    for (int o = 128; o; o >>= 1) {
        if (threadIdx.x < o) sm[threadIdx.x] += sm[threadIdx.x + o];
        __syncthreads();
    }
    if (threadIdx.x == 0) out[b] = sm[0] / fmaxf((float)(hi - lo), 1.0f);
}

static inline size_t algn(size_t x) { return (x + 255) & ~(size_t)255; }

extern "C" void kernel_launch(void* const* d_in, const int* in_sizes, int n_in,
                              void* d_out, int out_size, void* d_ws, size_t ws_size,
                              hipStream_t stream) {
    const float* state  = (const float*)d_in[0];
    const float* action = (const float*)d_in[1];
    const int*   eidx   = (const int*)d_in[2];
    const float* eattr  = (const float*)d_in[3];
    const int*   batch  = (const int*)d_in[4];
    const float* Win    = (const float*)d_in[5];
    const float* bin    = (const float*)d_in[6];
    const float* Wtaps  = (const float*)d_in[7];
    const float* bgnn   = (const float*)d_in[8];
    const float* Wout   = (const float*)d_in[9];
    const float* bout   = (const float*)d_in[10];
    float* out = (float*)d_out;

    const int N = in_sizes[0] / 8;       // SD=8
    const int E = in_sizes[3];
    const int B = out_size;
    const int K = 4, L = 2;
    const int NBK = (N + 255) >> BSH;

    const int* row = eidx;
    const int* col = eidx + E;

    // ---- workspace layout ----
    char* base = (char*)d_ws;
    int* ghist = (int*)base;                    // MAXBK, zeroed
    int* gcur  = ghist + MAXBK;                 // written by bscan
    size_t zbytes = (size_t)MAXBK * 4;
    char* p = base + algn((size_t)2 * MAXBK * 4);
    int*   bbase  = (int*)p;  p += algn((size_t)(MAXBK + 1) * 4);
    int*   rowptr = (int*)p;  p += algn((size_t)(N + 1) * 4);
    float* dinv   = (float*)p; p += algn((size_t)N * 4);
    int2*  pairs  = (int2*)p;  p += algn((size_t)E * 8);
    // aliased region: h (N*128B) | vhlo (N*32B) | vhhi | vAlo | vAhi  >= tmp (E*8)
    size_t region = (size_t)N * (128 + 32 + 32 + 32 + 32);
    if ((size_t)E * 8 > region) region = (size_t)E * 8;
    float*    h    = (float*)p;
    unsigned* vhlo = (unsigned*)(p + (size_t)N * 128);
    unsigned* vhhi = (unsigned*)(p + (size_t)N * 160);
    unsigned* vAlo = (unsigned*)(p + (size_t)N * 192);
    unsigned* vAhi = (unsigned*)(p + (size_t)N * 224);
    int2*     tmp  = (int2*)p;  p += algn(region);
    unsigned* vBlo = (unsigned*)p; p += algn((size_t)N * 32);
    unsigned* vBhi = (unsigned*)p; p += algn((size_t)N * 32);
    fv2*      zA   = (fv2*)p;   p += algn((size_t)N * 64);
    float* outacc = (float*)p; p += algn((size_t)N * C * 4);
    float* yv     = (float*)p; p += algn((size_t)N * 4);
    (void)ws_size; (void)n_in;

    const int BT = 256;
    const int gNC = ((size_t)N * 32 + BT - 1) / BT;
    const int gN8 = ((size_t)N * 8 + BT - 1) / BT;

    hipMemsetAsync(d_ws, 0, zbytes, stream);

    k_bhist<<<512, BT, 0, stream>>>(col, ghist, E);
    k_bscan<<<1, MAXBK, 0, stream>>>(ghist, bbase, gcur, NBK, E);
    k_part<<<256, 1024, 0, stream>>>(row, col, eattr, gcur, tmp, E);
    k_build<<<NBK, 256, 0, stream>>>(bbase, tmp, rowptr, dinv, pairs, N, E);

    k_inmlp<<<gNC, BT, 0, stream>>>(state, action, Win, bin, dinv, h, vhlo, vhhi, N);

    for (int l = 0; l < L; ++l) {
        const float* Wl = Wtaps + (size_t)l * (K + 1) * 32 * 32;
        const float* bl = bgnn + (size_t)l * 32;
        const unsigned* vinLo = vhlo;
        const unsigned* vinHi = vhhi;
        for (int k = 1; k <= K; ++k) {
            int first = (k == 1);
            int last  = (k == K);
            int rdout = last && (l == L - 1);
            unsigned* voutLo = (k & 1) ? vAlo : vBlo;   // unused when last
            unsigned* voutHi = (k & 1) ? vAhi : vBhi;
            k_tapA<<<gN8, BT, 0, stream>>>(rowptr, pairs, vinLo, dinv, zA,
                                           voutLo, N, last);
            k_tapB<<<gN8, BT, 0, stream>>>(rowptr, pairs, vinHi, h, dinv, zA,
                                           outacc, voutHi, vhlo, vhhi, h, yv,
                                           Wl, k, bl, Wout, bout,
                                           N, first, last, rdout);
            vinLo = voutLo;
            vinHi = voutHi;
        }
    }

    k_segmean<<<B, 256, 0, stream>>>(yv, batch, out, N);
}

// Round 11
// 750.366 us; speedup vs baseline: 1.2870x; 1.2870x over previous
//
#include <hip/hip_runtime.h>

#define LRELU(x) ((x) > 0.f ? (x) : 0.01f * (x))

constexpr int C = 32;
constexpr int BSH = 8;            // 256 dst-nodes per bucket
constexpr int MAXBK = 512;        // max buckets (N <= 131072)

typedef int   iv4 __attribute__((ext_vector_type(4)));
typedef float fv4 __attribute__((ext_vector_type(4)));

// ---- bf16 pack/unpack helpers ----
__device__ __forceinline__ unsigned pk_bf16(float a, float b) {
    unsigned ua = __float_as_uint(a), ub = __float_as_uint(b);
    unsigned ra = (ua + 0x7fffu + ((ua >> 16) & 1u)) >> 16;
    unsigned rb = (ub + 0x7fffu + ((ub >> 16) & 1u)) & 0xffff0000u;
    return ra | rb;
}
__device__ __forceinline__ float lo_bf16(unsigned w) { return __uint_as_float(w << 16); }
__device__ __forceinline__ float hi_bf16(unsigned w) { return __uint_as_float(w & 0xffff0000u); }

// ---- bucket histogram (LDS-privatized) ----
__global__ void k_bhist(const int* __restrict__ col, int* __restrict__ ghist, int E) {
    __shared__ int lh[MAXBK];
    for (int i = threadIdx.x; i < MAXBK; i += blockDim.x) lh[i] = 0;
    __syncthreads();
    int chunk = (E + gridDim.x - 1) / gridDim.x;
    int c0 = blockIdx.x * chunk, c1 = min(E, c0 + chunk);
    for (int e = c0 + threadIdx.x; e < c1; e += blockDim.x)
        atomicAdd(&lh[col[e] >> BSH], 1);
    __syncthreads();
    for (int i = threadIdx.x; i < MAXBK; i += blockDim.x) {
        int v = lh[i];
        if (v) atomicAdd(&ghist[i], v);
    }
}

// ---- exclusive scan of bucket counts -> bbase, gcur ----
__global__ void k_bscan(const int* __restrict__ ghist, int* __restrict__ bbase,
                        int* __restrict__ gcur, int nbk, int E) {
    __shared__ int sm[MAXBK];
    int tid = threadIdx.x;
    int v = (tid < nbk) ? ghist[tid] : 0;
    sm[tid] = v;
    __syncthreads();
    for (int off = 1; off < MAXBK; off <<= 1) {
        int t = (tid >= off) ? sm[tid - off] : 0;
        __syncthreads();
        sm[tid] += t;
        __syncthreads();
    }
    if (tid < nbk) {
        int excl = sm[tid] - v;
        bbase[tid] = excl;
        gcur[tid] = excl;
    }
    if (tid == 0) bbase[nbk] = E;
}

// ---- partition edges into buckets; per-wg claimed contiguous runs ----
// tmp entry: { src | (dstLow8 << 17), ea_bits }
__global__ void k_part(const int* __restrict__ row, const int* __restrict__ col,
                       const float* __restrict__ ea, int* __restrict__ gcur,
                       int2* __restrict__ tmp, int E) {
    __shared__ int lcnt[MAXBK];
    __shared__ int lbase[MAXBK];
    __shared__ int lcur[MAXBK];
    for (int i = threadIdx.x; i < MAXBK; i += blockDim.x) { lcnt[i] = 0; lcur[i] = 0; }
    __syncthreads();
    int chunk = (E + gridDim.x - 1) / gridDim.x;
    int c0 = blockIdx.x * chunk, c1 = min(E, c0 + chunk);
    for (int e = c0 + threadIdx.x; e < c1; e += blockDim.x)
        atomicAdd(&lcnt[col[e] >> BSH], 1);
    __syncthreads();
    for (int b = threadIdx.x; b < MAXBK; b += blockDim.x) {
        int c = lcnt[b];
        lbase[b] = c ? atomicAdd(&gcur[b], c) : 0;
    }
    __syncthreads();
    for (int e = c0 + threadIdx.x; e < c1; e += blockDim.x) {
        int cc = col[e];
        int b = cc >> BSH;
        int r = atomicAdd(&lcur[b], 1);
        tmp[lbase[b] + r] = make_int2(row[e] | ((cc & 255) << 17), __float_as_int(ea[e]));
    }
}

// ---- per-bucket CSR build; rows ordered {src<Nh first}, rowmid = split point ----
__global__ void k_build(const int* __restrict__ bbase, const int2* __restrict__ tmp,
                        int* __restrict__ rowptr, int* __restrict__ rowmid,
                        float* __restrict__ dinv, int2* __restrict__ pairs,
                        int N, int Nh, int E) {
    __shared__ int ncnt[512], noff[512], ncur[512];
    __shared__ int tsum[256];
    __shared__ float ndeg[256];
    int tid = threadIdx.x;
    int bg = blockIdx.x;
    int node0 = bg << BSH;
    int s = bbase[bg], e = bbase[bg + 1];
    ncnt[tid] = 0; ncnt[tid + 256] = 0;
    ncur[tid] = 0; ncur[tid + 256] = 0;
    ndeg[tid] = 0.f;
    __syncthreads();
    for (int p = s + tid; p < e; p += 256) {
        int2 u = tmp[p];
        int nl = (u.x >> 17) & 255;
        int src = u.x & 0x1FFFF;
        int hl = src >= Nh;
        atomicAdd(&ncnt[nl * 2 + hl], 1);
        atomicAdd(&ndeg[nl], __int_as_float(u.y));
    }
    __syncthreads();
    int c0 = ncnt[2 * tid], c1 = ncnt[2 * tid + 1];
    int mysum = c0 + c1;
    tsum[tid] = mysum;
    __syncthreads();
    for (int off = 1; off < 256; off <<= 1) {
        int t = (tid >= off) ? tsum[tid - off] : 0;
        __syncthreads();
        tsum[tid] += t;
        __syncthreads();
    }
    {
        int base = tsum[tid] - mysum;
        noff[2 * tid] = base;
        noff[2 * tid + 1] = base + c0;
        int node = node0 + tid;
        if (node < N) {
            rowptr[node] = s + base;
            rowmid[node] = s + base + c0;
            float d = ndeg[tid];
            dinv[node] = d > 0.f ? rsqrtf(fmaxf(d, 1e-12f)) : 0.f;
        }
    }
    if (bg == gridDim.x - 1 && tid == 0) rowptr[N] = E;
    __syncthreads();
    for (int p = s + tid; p < e; p += 256) {
        int2 u = tmp[p];
        int nl = (u.x >> 17) & 255;
        int src = u.x & 0x1FFFF;
        int hl = src >= Nh;
        int r = atomicAdd(&ncur[nl * 2 + hl], 1);
        pairs[s + noff[nl * 2 + hl] + r] = make_int2(src, u.y);
    }
}

// ---- read-in MLP: h = lrelu([state,action]@W_in+b_in); v = bf16(dinv*h) ----
__global__ void k_inmlp(const float* __restrict__ state, const float* __restrict__ action,
                        const float* __restrict__ Win, const float* __restrict__ bin,
                        const float* __restrict__ dinv,
                        float* __restrict__ h, unsigned* __restrict__ v, int N) {
    int t = blockIdx.x * blockDim.x + threadIdx.x;
    int i = t >> 5, c = t & 31;
    if (i >= N) return;
    float acc = bin[c];
#pragma unroll
    for (int d = 0; d < 8; ++d) acc += state[i * 8 + d] * Win[d * 32 + c];
#pragma unroll
    for (int d = 0; d < 2; ++d) acc += action[i * 2 + d] * Win[(8 + d) * 32 + c];
    float hv = LRELU(acc);
    h[i * 32 + c] = hv;
    float vv = dinv[i] * hv;
    float other = __shfl_xor(vv, 1, 32);
    if ((c & 1) == 0) v[(size_t)i * 16 + (c >> 1)] = pk_bf16(vv, other);
}

__device__ __forceinline__ void edge_acc(float4& tv, float w, uint2 x) {
    tv.x += w * lo_bf16(x.x); tv.y += w * hi_bf16(x.x);
    tv.z += w * lo_bf16(x.y); tv.w += w * hi_bf16(x.y);
}

// ---- gather edges [p, e): 4-edge int4 chunks (R6-best shape) ----
__device__ __forceinline__ float4 gather_range(int p, int e, const int2* __restrict__ pairs,
                                               const uint2* __restrict__ vin, int q) {
    float4 tv = {0.f, 0.f, 0.f, 0.f};
    if ((p & 1) && p < e) {                 // peel to 16B-aligned pair index
        int2 pr = pairs[p];
        uint2 x = vin[((size_t)(unsigned)pr.x << 3) + q];
        edge_acc(tv, __int_as_float(pr.y), x);
        ++p;
    }
#pragma unroll 2
    for (; p + 4 <= e; p += 4) {
        iv4 pa = __builtin_nontemporal_load((const iv4*)&pairs[p]);
        iv4 pb = __builtin_nontemporal_load((const iv4*)&pairs[p + 2]);
        uint2 x0 = vin[((size_t)(unsigned)pa[0] << 3) + q];
        uint2 x1 = vin[((size_t)(unsigned)pa[2] << 3) + q];
        uint2 x2 = vin[((size_t)(unsigned)pb[0] << 3) + q];
        uint2 x3 = vin[((size_t)(unsigned)pb[2] << 3) + q];
        edge_acc(tv, __int_as_float(pa[1]), x0);
        edge_acc(tv, __int_as_float(pa[3]), x1);
        edge_acc(tv, __int_as_float(pb[1]), x2);
        edge_acc(tv, __int_as_float(pb[3]), x3);
    }
    for (; p < e; ++p) {
        int2 pr = pairs[p];
        uint2 x = vin[((size_t)(unsigned)pr.x << 3) + q];
        edge_acc(tv, __int_as_float(pr.y), x);
    }
    return tv;
}

// ---- tap pass 1: edges with src < N/2 (hot table half L2-resident); partial sums ----
__global__ void k_tapP1(const int* __restrict__ rowptr, const int* __restrict__ rowmid,
                        const int2* __restrict__ pairs, const uint2* __restrict__ vin,
                        fv4* __restrict__ zPart, int N) {
    int t = blockIdx.x * blockDim.x + threadIdx.x;
    int g = t >> 3, q = t & 7;
    if (g >= N) return;
    float4 tv = gather_range(rowptr[g], rowmid[g], pairs, vin, q);
    fv4 z = {tv.x, tv.y, tv.z, tv.w};
    __builtin_nontemporal_store(z, &zPart[((size_t)g << 3) + q]);
}

// acc(4 cols) += z(row, spread over 8 lanes as float4) @ W(32x32), cols 4q..4q+3
__device__ __forceinline__ void mm_acc(float4& acc, float4 zq,
                                       const float* __restrict__ W, int q) {
#pragma unroll
    for (int a = 0; a < 8; ++a) {
        float z0 = __shfl(zq.x, a, 8), z1 = __shfl(zq.y, a, 8);
        float z2 = __shfl(zq.z, a, 8), z3 = __shfl(zq.w, a, 8);
        const float4 w0 = *(const float4*)&W[(4 * a + 0) * 32 + 4 * q];
        const float4 w1 = *(const float4*)&W[(4 * a + 1) * 32 + 4 * q];
        const float4 w2 = *(const float4*)&W[(4 * a + 2) * 32 + 4 * q];
        const float4 w3 = *(const float4*)&W[(4 * a + 3) * 32 + 4 * q];
        acc.x += z0 * w0.x + z1 * w1.x + z2 * w2.x + z3 * w3.x;
        acc.y += z0 * w0.y + z1 * w1.y + z2 * w2.y + z3 * w3.y;
        acc.z += z0 * w0.z + z1 * w1.z + z2 * w2.z + z3 * w3.z;
        acc.w += z0 * w0.w + z1 * w1.w + z2 * w2.w + z3 * w3.w;
    }
}

// ---- tap pass 2: edges with src >= N/2; combine partials; matmul + epilogue ----
__global__ void k_tapP2(const int* __restrict__ rowptr, const int* __restrict__ rowmid,
                        const int2* __restrict__ pairs, const uint2* __restrict__ vin,
                        const float* __restrict__ hin, const float* __restrict__ dinv,
                        const fv4* __restrict__ zPart,
                        float* __restrict__ outacc, uint2* __restrict__ vout,
                        float* __restrict__ hout, float* __restrict__ yout,
                        const float* __restrict__ Wl, int k, const float* __restrict__ bias,
                        const float* __restrict__ Wout, const float* __restrict__ bout,
                        int N, int first, int last, int readout) {
    int t = blockIdx.x * blockDim.x + threadIdx.x;
    int g = t >> 3, q = t & 7;
    if (g >= N) return;
    float4 tv = gather_range(rowmid[g], rowptr[g + 1], pairs, vin, q);
    fv4 zp = __builtin_nontemporal_load(&zPart[((size_t)g << 3) + q]);
    tv.x += zp.x; tv.y += zp.y; tv.z += zp.z; tv.w += zp.w;
    float di = dinv[g];
    float4 z = {di * tv.x, di * tv.y, di * tv.z, di * tv.w};
    const float* Wk = Wl + (size_t)k * 1024;
    float4 acc;
    if (first) {
        acc = *(const float4*)&bias[4 * q];
        float4 hq = *(const float4*)&hin[(size_t)g * 32 + 4 * q];
        mm_acc(acc, hq, Wl, q);
    } else {
        acc = *(const float4*)&outacc[(size_t)g * 32 + 4 * q];
    }
    mm_acc(acc, z, Wk, q);
    if (!last) {
        *(float4*)&outacc[(size_t)g * 32 + 4 * q] = acc;
        vout[((size_t)g << 3) + q] = make_uint2(pk_bf16(di * z.x, di * z.y),
                                                pk_bf16(di * z.z, di * z.w));
    } else {
        float4 hv = {LRELU(acc.x), LRELU(acc.y), LRELU(acc.z), LRELU(acc.w)};
        if (!readout) {
            *(float4*)&hout[(size_t)g * 32 + 4 * q] = hv;
            vout[((size_t)g << 3) + q] = make_uint2(pk_bf16(di * hv.x, di * hv.y),
                                                    pk_bf16(di * hv.z, di * hv.w));
        } else {
            const float4 w4 = *(const float4*)&Wout[4 * q];
            float v = hv.x * w4.x + hv.y * w4.y + hv.z * w4.z + hv.w * w4.w;
            v += __shfl_xor(v, 4, 8);
            v += __shfl_xor(v, 2, 8);
            v += __shfl_xor(v, 1, 8);
            if (q == 0) yout[g] = v + bout[0];
        }
    }
}

// ---- segmented mean over sorted batch: one block per graph ----
__global__ void k_segmean(const float* __restrict__ y, const int* __restrict__ batch,
                          float* __restrict__ out, int N) {
    int b = blockIdx.x;
    __shared__ int slo, shi;
    if (threadIdx.x == 0) {
        int lo = 0, hi = N;
        while (lo < hi) { int m = (lo + hi) >> 1; if (batch[m] < b) lo = m + 1; else hi = m; }
        slo = lo;
        hi = N;
        while (lo < hi) { int m = (lo + hi) >> 1; if (batch[m] < b + 1) lo = m + 1; else hi = m; }
        shi = lo;
    }
    __syncthreads();
    int lo = slo, hi = shi;
    float sum = 0.f;
    for (int i = lo + threadIdx.x; i < hi; i += blockDim.x) sum += y[i];
    __shared__ float sm[256];
    sm[threadIdx.x] = sum;
    __syncthreads();
    for (int o = 128; o; o >>= 1) {
        if (threadIdx.x < o) sm[threadIdx.x] += sm[threadIdx.x + o];
        __syncthreads();
    }
    if (threadIdx.x == 0) out[b] = sm[0] / fmaxf((float)(hi - lo), 1.0f);
}

static inline size_t algn(size_t x) { return (x + 255) & ~(size_t)255; }

extern "C" void kernel_launch(void* const* d_in, const int* in_sizes, int n_in,
                              void* d_out, int out_size, void* d_ws, size_t ws_size,
                              hipStream_t stream) {
    const float* state  = (const float*)d_in[0];
    const float* action = (const float*)d_in[1];
    const int*   eidx   = (const int*)d_in[2];
    const float* eattr  = (const float*)d_in[3];
    const int*   batch  = (const int*)d_in[4];
    const float* Win    = (const float*)d_in[5];
    const float* bin    = (const float*)d_in[6];
    const float* Wtaps  = (const float*)d_in[7];
    const float* bgnn   = (const float*)d_in[8];
    const float* Wout   = (const float*)d_in[9];
    const float* bout   = (const float*)d_in[10];
    float* out = (float*)d_out;

    const int N = in_sizes[0] / 8;       // SD=8
    const int E = in_sizes[3];
    const int B = out_size;
    const int K = 4, L = 2;
    const int NBK = (N + 255) >> BSH;
    const int Nh = (N + 1) >> 1;

    const int* row = eidx;
    const int* col = eidx + E;

    // ---- workspace layout ----
    char* base = (char*)d_ws;
    int* ghist = (int*)base;                    // MAXBK, zeroed
    int* gcur  = ghist + MAXBK;                 // written by bscan
    size_t zbytes = (size_t)MAXBK * 4;
    char* p = base + algn((size_t)2 * MAXBK * 4);
    int*   bbase  = (int*)p;  p += algn((size_t)(MAXBK + 1) * 4);
    int*   rowptr = (int*)p;  p += algn((size_t)(N + 1) * 4);
    int*   rowmid = (int*)p;  p += algn((size_t)N * 4);
    float* dinv   = (float*)p; p += algn((size_t)N * 4);
    int2*  pairs  = (int2*)p;  p += algn((size_t)E * 8);
    // region: h (f32, N*32) | vh (bf16, N*16 u32) | vA (bf16) — aliased by tmp
    size_t region = (size_t)N * (128 + 64 + 64);
    if ((size_t)E * 8 > region) region = (size_t)E * 8;
    float*    h   = (float*)p;
    unsigned* vh  = (unsigned*)(p + (size_t)N * 128);
    unsigned* vA  = (unsigned*)(p + (size_t)N * 192);
    int2*     tmp = (int2*)p;  p += algn(region);
    unsigned* vB  = (unsigned*)p; p += algn((size_t)N * 64);
    float* outacc = (float*)p; p += algn((size_t)N * C * 4);
    fv4*   zPart  = (fv4*)p;   p += algn((size_t)N * C * 4);
    float* yv     = (float*)p; p += algn((size_t)N * 4);
    (void)ws_size; (void)n_in;

    const int BT = 256;
    const int gNC = ((size_t)N * 32 + BT - 1) / BT;
    const int gN8 = ((size_t)N * 8 + BT - 1) / BT;

    hipMemsetAsync(d_ws, 0, zbytes, stream);

    k_bhist<<<512, BT, 0, stream>>>(col, ghist, E);
    k_bscan<<<1, MAXBK, 0, stream>>>(ghist, bbase, gcur, NBK, E);
    k_part<<<256, 1024, 0, stream>>>(row, col, eattr, gcur, tmp, E);
    k_build<<<NBK, 256, 0, stream>>>(bbase, tmp, rowptr, rowmid, dinv, pairs, N, Nh, E);

    k_inmlp<<<gNC, BT, 0, stream>>>(state, action, Win, bin, dinv, h, vh, N);

    for (int l = 0; l < L; ++l) {
        const float* Wl = Wtaps + (size_t)l * (K + 1) * 32 * 32;
        const float* bl = bgnn + (size_t)l * 32;
        const unsigned* vin = vh;
        for (int k = 1; k <= K; ++k) {
            int first = (k == 1);
            int last  = (k == K);
            int rdout = last && (l == L - 1);
            unsigned* vout = last ? vh : ((k & 1) ? vA : vB);
            k_tapP1<<<gN8, BT, 0, stream>>>(rowptr, rowmid, pairs, (const uint2*)vin,
                                            zPart, N);
            k_tapP2<<<gN8, BT, 0, stream>>>(rowptr, rowmid, pairs, (const uint2*)vin,
                                            h, dinv, zPart, outacc, (uint2*)vout,
                                            h, yv, Wl, k, bl, Wout, bout,
                                            N, first, last, rdout);
            vin = vout;
        }
    }

    k_segmean<<<B, 256, 0, stream>>>(yv, batch, out, N);
}